// Round 21
// baseline (1884.763 us; speedup 1.0000x reference)
//
#include <hip/hip_runtime.h>
#include <math.h>

#define T_DIM 1024
#define B_DIM 256
#define D_DIM 32
#define H_DIM 128

// Bit-faithful XLA-CPU / Eigen fast-tanh, WITH-FMA variant — FROZEN.
// Verified bit-exact vs the harness reference (absmax 0.0, rounds 15-20).
__device__ __forceinline__ float xla_tanh_fma_f32(float x) {
  const float plim = 7.99881172180175781f;
  float xc = fminf(fmaxf(x, -plim), plim);
  float x2 = __fmul_rn(xc, xc);
  float p;
  p = fmaf(x2, -2.76076847742355e-16f, 2.00018790482477e-13f);
  p = fmaf(x2, p, -8.60467152213735e-11f);
  p = fmaf(x2, p,  5.12229709037114e-08f);
  p = fmaf(x2, p,  1.48572235717979e-05f);
  p = fmaf(x2, p,  6.37261928875436e-04f);
  p = fmaf(x2, p,  4.89352455891786e-03f);
  float num = __fmul_rn(xc, p);
  float q;
  q = fmaf(x2, 1.19825839466702e-06f, 1.18534705686654e-04f);
  q = fmaf(x2, q, 2.26843463243900e-03f);
  q = fmaf(x2, q, 4.89352518554385e-03f);
  float r = __fdiv_rn(num, q);
  return (fabsf(x) < 0.0004f) ? x : r;
}

#define AG_STR_(x) #x
#define AG_STR(x) AG_STR_(x)

// Stash one f32 into a HARD-CODED AGPR. Clobber tells the allocator the
// AGPR is taken (sets .agpr_count); explicit index means no heuristic can
// spill or rematerialize it — this defeats the 96-VGPR reload behavior
// that R17-R20 could not move (4 source variants, identical binaries).
#define STW(N, val) \
  asm volatile("v_accvgpr_write_b32 a" AG_STR(N) ", %0" :: "v"(val) : "a" AG_STR(N));
// Volatile read: executes exactly once per use site, never hoisted/CSE'd
// (hoisting would re-create register pressure and spill).
#define RDA(N, dst) \
  asm volatile("v_accvgpr_read_b32 %0, a" AG_STR(N) : "=v"(dst));

// (q, 4q+0..4q+3) literal tables — asm register names need literals.
#define Q_LIST(M) \
  M(0,0,1,2,3) M(1,4,5,6,7) M(2,8,9,10,11) M(3,12,13,14,15) \
  M(4,16,17,18,19) M(5,20,21,22,23) M(6,24,25,26,27) M(7,28,29,30,31) \
  M(8,32,33,34,35) M(9,36,37,38,39) M(10,40,41,42,43) M(11,44,45,46,47) \
  M(12,48,49,50,51) M(13,52,53,54,55) M(14,56,57,58,59) M(15,60,61,62,63) \
  M(16,64,65,66,67) M(17,68,69,70,71) M(18,72,73,74,75) M(19,76,77,78,79) \
  M(20,80,81,82,83) M(21,84,85,86,87) M(22,88,89,90,91) M(23,92,93,94,95) \
  M(24,96,97,98,99) M(25,100,101,102,103) M(26,104,105,106,107) \
  M(27,108,109,110,111) M(28,112,113,114,115) M(29,116,117,118,119) \
  M(30,120,121,122,123) M(31,124,125,126,127)
#define X_LIST(M) \
  M(0,128,129,130,131) M(1,132,133,134,135) M(2,136,137,138,139) \
  M(3,140,141,142,143) M(4,144,145,146,147) M(5,148,149,150,151) \
  M(6,152,153,154,155) M(7,156,157,158,159)

#define REP8(M)  M(0) M(1) M(2) M(3) M(4) M(5) M(6) M(7)

__global__ __launch_bounds__(128, 1) void diffeq_kernel(
    const float* __restrict__ x, const float* __restrict__ state,
    const float* __restrict__ W_in, const float* __restrict__ W_h,
    const float* __restrict__ bias, float* __restrict__ out) {
  __shared__ __align__(16) float h0[H_DIM];
  __shared__ __align__(16) float h1[H_DIM];

  const int b = blockIdx.x;
  const int j = threadIdx.x;                   // output index 0..127

  // ---- W_h column j -> AGPRs a0..a127; W_in column j -> a128..a159 ----
#define L_WH(q, n0, n1, n2, n3) { \
    float v0 = W_h[(4*(q)+0)*H_DIM+j]; STW(n0, v0) \
    float v1 = W_h[(4*(q)+1)*H_DIM+j]; STW(n1, v1) \
    float v2 = W_h[(4*(q)+2)*H_DIM+j]; STW(n2, v2) \
    float v3 = W_h[(4*(q)+3)*H_DIM+j]; STW(n3, v3) }
  Q_LIST(L_WH)
#define L_WX(q, n0, n1, n2, n3) { \
    float v0 = W_in[(4*(q)+0)*H_DIM+j]; STW(n0, v0) \
    float v1 = W_in[(4*(q)+1)*H_DIM+j]; STW(n1, v1) \
    float v2 = W_in[(4*(q)+2)*H_DIM+j]; STW(n2, v2) \
    float v3 = W_in[(4*(q)+3)*H_DIM+j]; STW(n3, v3) }
  X_LIST(L_WX)
  const float bj = bias[j];

  float hown = state[(size_t)b * H_DIM + j];   // own h_j carried in register
  h0[j] = hown;
  __syncthreads();

  const size_t out_row = (size_t)b * H_DIM + j;
  const float4* xg4 = reinterpret_cast<const float4*>(x + (size_t)b * D_DIM);
  const int xstride4 = B_DIM * D_DIM / 4;      // 2048 float4 per t

  // x rows double-buffered in named registers (uniform addrs; L2-resident).
#define D_XA(i) float4 xa##i;
#define D_XB(i) float4 xb##i;
  REP8(D_XA) REP8(D_XB)
#define PF_X0(i) xa##i = xg4[i];
  REP8(PF_X0)

  // ---- per-step macros (ARITHMETIC FROZEN: serial ascending-k fmaf) ----
#define S1A(q, n0, n1, n2, n3) { float w0, w1, w2, w3; \
    RDA(n0, w0) RDA(n1, w1) RDA(n2, w2) RDA(n3, w3) \
    s1 = fmaf(xa##q.x, w0, s1); s1 = fmaf(xa##q.y, w1, s1); \
    s1 = fmaf(xa##q.z, w2, s1); s1 = fmaf(xa##q.w, w3, s1); }
#define S1B(q, n0, n1, n2, n3) { float w0, w1, w2, w3; \
    RDA(n0, w0) RDA(n1, w1) RDA(n2, w2) RDA(n3, w3) \
    s1 = fmaf(xb##q.x, w0, s1); s1 = fmaf(xb##q.y, w1, s1); \
    s1 = fmaf(xb##q.z, w2, s1); s1 = fmaf(xb##q.w, w3, s1); }
#define S2Q(q, n0, n1, n2, n3) { float4 h4 = hq4[q]; float w0, w1, w2, w3; \
    RDA(n0, w0) RDA(n1, w1) RDA(n2, w2) RDA(n3, w3) \
    s2 = fmaf(h4.x, w0, s2); s2 = fmaf(h4.y, w1, s2); \
    s2 = fmaf(h4.z, w2, s2); s2 = fmaf(h4.w, w3, s2); }
#define PF_XB(i) xb##i = xg4[(size_t)(t + 1) * xstride4 + (i)];
#define PF_XA(i) xa##i = xg4[(size_t)(t + 2) * xstride4 + (i)];

  for (int t = 0; t < T_DIM; t += 2) {
    // ---- even step: reads h0, consumes xa, writes h1; prefetch xb(t+1) ----
    REP8(PF_XB)
    {
      const float4* hq4 = reinterpret_cast<const float4*>(h0);
      float s1 = 0.f;
      X_LIST(S1A)
      float s2 = 0.f;
      Q_LIST(S2Q)
      float a  = __fadd_rn(__fadd_rn(s1, s2), bj);
      float th = xla_tanh_fma_f32(a);
      hown = __fadd_rn(hown, th);
      h1[j] = hown;
      __syncthreads();
      // store AFTER barrier: vmcnt drain hides under the next step.
      out[(size_t)t * (B_DIM * H_DIM) + out_row] = hown;
    }
    // ---- odd step: reads h1, consumes xb, writes h0; prefetch xa(t+2) ----
    if (t + 2 < T_DIM) { REP8(PF_XA) }
    {
      const float4* hq4 = reinterpret_cast<const float4*>(h1);
      float s1 = 0.f;
      X_LIST(S1B)
      float s2 = 0.f;
      Q_LIST(S2Q)
      float a  = __fadd_rn(__fadd_rn(s1, s2), bj);
      float th = xla_tanh_fma_f32(a);
      hown = __fadd_rn(hown, th);
      h0[j] = hown;
      __syncthreads();
      out[(size_t)(t + 1) * (B_DIM * H_DIM) + out_row] = hown;
    }
  }

  // final_state = h after last step (== outputs[T-1])
  out[(size_t)T_DIM * B_DIM * H_DIM + out_row] = hown;
}

extern "C" void kernel_launch(void* const* d_in, const int* in_sizes, int n_in,
                              void* d_out, int out_size, void* d_ws, size_t ws_size,
                              hipStream_t stream) {
  const float* x     = (const float*)d_in[0];
  const float* state = (const float*)d_in[1];
  const float* W_in  = (const float*)d_in[2];
  const float* W_h   = (const float*)d_in[3];
  const float* bias  = (const float*)d_in[4];
  float* out = (float*)d_out;

  diffeq_kernel<<<B_DIM, 128, 0, stream>>>(x, state, W_in, W_h, bias, out);
}

// Round 22
// 1326.754 us; speedup vs baseline: 1.4206x; 1.4206x over previous
//
#include <hip/hip_runtime.h>
#include <math.h>

#define T_DIM 1024
#define B_DIM 256
#define D_DIM 32
#define H_DIM 128

// Bit-faithful XLA-CPU / Eigen fast-tanh, WITH-FMA variant — FROZEN.
// Verified bit-exact vs the harness reference (absmax 0.0, rounds 15-21).
__device__ __forceinline__ float xla_tanh_fma_f32(float x) {
  const float plim = 7.99881172180175781f;
  float xc = fminf(fmaxf(x, -plim), plim);
  float x2 = __fmul_rn(xc, xc);
  float p;
  p = fmaf(x2, -2.76076847742355e-16f, 2.00018790482477e-13f);
  p = fmaf(x2, p, -8.60467152213735e-11f);
  p = fmaf(x2, p,  5.12229709037114e-08f);
  p = fmaf(x2, p,  1.48572235717979e-05f);
  p = fmaf(x2, p,  6.37261928875436e-04f);
  p = fmaf(x2, p,  4.89352455891786e-03f);
  float num = __fmul_rn(xc, p);
  float q;
  q = fmaf(x2, 1.19825839466702e-06f, 1.18534705686654e-04f);
  q = fmaf(x2, q, 2.26843463243900e-03f);
  q = fmaf(x2, q, 4.89352518554385e-03f);
  float r = __fdiv_rn(num, q);
  return (fabsf(x) < 0.0004f) ? x : r;
}

#define AG_STR_(x) #x
#define AG_STR(x) AG_STR_(x)

// Prologue-only stash into a HARD-CODED AGPR (volatile is fine here: runs
// once). Clobber reserves the AGPR from the allocator.
#define STW(N, val) \
  asm volatile("v_accvgpr_write_b32 a" AG_STR(N) ", %0" :: "v"(val) : "a" AG_STR(N));

// NON-volatile AGPR read (the R21 fix): the scheduler may freely hoist/
// interleave it into the FMA chain's dependency gaps (2-4 cyc latency vs
// ~200 cyc L1 weight reloads). The dummy SGPR input `dep_` (varies per
// half-iteration) blocks loop-invariant hoisting and cross-half CSE that
// would recreate the 160-live-value pressure; outputs feed FMAs so DCE
// cannot remove it.
#define RDA(N, dst) \
  asm("v_accvgpr_read_b32 %0, a" AG_STR(N) : "=v"(dst) : "s"(dep_));

// (q, 4q+0..4q+3) literal tables — asm register names need literals.
#define Q_LIST(M) \
  M(0,0,1,2,3) M(1,4,5,6,7) M(2,8,9,10,11) M(3,12,13,14,15) \
  M(4,16,17,18,19) M(5,20,21,22,23) M(6,24,25,26,27) M(7,28,29,30,31) \
  M(8,32,33,34,35) M(9,36,37,38,39) M(10,40,41,42,43) M(11,44,45,46,47) \
  M(12,48,49,50,51) M(13,52,53,54,55) M(14,56,57,58,59) M(15,60,61,62,63) \
  M(16,64,65,66,67) M(17,68,69,70,71) M(18,72,73,74,75) M(19,76,77,78,79) \
  M(20,80,81,82,83) M(21,84,85,86,87) M(22,88,89,90,91) M(23,92,93,94,95) \
  M(24,96,97,98,99) M(25,100,101,102,103) M(26,104,105,106,107) \
  M(27,108,109,110,111) M(28,112,113,114,115) M(29,116,117,118,119) \
  M(30,120,121,122,123) M(31,124,125,126,127)
#define X_LIST(M) \
  M(0,128,129,130,131) M(1,132,133,134,135) M(2,136,137,138,139) \
  M(3,140,141,142,143) M(4,144,145,146,147) M(5,148,149,150,151) \
  M(6,152,153,154,155) M(7,156,157,158,159)

#define REP8(M)  M(0) M(1) M(2) M(3) M(4) M(5) M(6) M(7)

__global__ __launch_bounds__(128, 1) void diffeq_kernel(
    const float* __restrict__ x, const float* __restrict__ state,
    const float* __restrict__ W_in, const float* __restrict__ W_h,
    const float* __restrict__ bias, float* __restrict__ out) {
  __shared__ __align__(16) float h0[H_DIM];
  __shared__ __align__(16) float h1[H_DIM];

  const int b = blockIdx.x;
  const int j = threadIdx.x;                   // output index 0..127

  // ---- W_h column j -> AGPRs a0..a127; W_in column j -> a128..a159 ----
#define L_WH(q, n0, n1, n2, n3) { \
    float v0 = W_h[(4*(q)+0)*H_DIM+j]; STW(n0, v0) \
    float v1 = W_h[(4*(q)+1)*H_DIM+j]; STW(n1, v1) \
    float v2 = W_h[(4*(q)+2)*H_DIM+j]; STW(n2, v2) \
    float v3 = W_h[(4*(q)+3)*H_DIM+j]; STW(n3, v3) }
  Q_LIST(L_WH)
#define L_WX(q, n0, n1, n2, n3) { \
    float v0 = W_in[(4*(q)+0)*H_DIM+j]; STW(n0, v0) \
    float v1 = W_in[(4*(q)+1)*H_DIM+j]; STW(n1, v1) \
    float v2 = W_in[(4*(q)+2)*H_DIM+j]; STW(n2, v2) \
    float v3 = W_in[(4*(q)+3)*H_DIM+j]; STW(n3, v3) }
  X_LIST(L_WX)
  const float bj = bias[j];

  float hown = state[(size_t)b * H_DIM + j];   // own h_j carried in register
  h0[j] = hown;
  __syncthreads();

  const size_t out_row = (size_t)b * H_DIM + j;
  const float4* xg4 = reinterpret_cast<const float4*>(x + (size_t)b * D_DIM);
  const int xstride4 = B_DIM * D_DIM / 4;      // 2048 float4 per t

  // x rows double-buffered in named registers (uniform addrs; L2-resident).
#define D_XA(i) float4 xa##i;
#define D_XB(i) float4 xb##i;
  REP8(D_XA) REP8(D_XB)
#define PF_X0(i) xa##i = xg4[i];
  REP8(PF_X0)

  // ---- per-step macros (ARITHMETIC FROZEN: serial ascending-k fmaf) ----
#define S1A(q, n0, n1, n2, n3) { float w0, w1, w2, w3; \
    RDA(n0, w0) RDA(n1, w1) RDA(n2, w2) RDA(n3, w3) \
    s1 = fmaf(xa##q.x, w0, s1); s1 = fmaf(xa##q.y, w1, s1); \
    s1 = fmaf(xa##q.z, w2, s1); s1 = fmaf(xa##q.w, w3, s1); }
#define S1B(q, n0, n1, n2, n3) { float w0, w1, w2, w3; \
    RDA(n0, w0) RDA(n1, w1) RDA(n2, w2) RDA(n3, w3) \
    s1 = fmaf(xb##q.x, w0, s1); s1 = fmaf(xb##q.y, w1, s1); \
    s1 = fmaf(xb##q.z, w2, s1); s1 = fmaf(xb##q.w, w3, s1); }
#define S2Q(q, n0, n1, n2, n3) { float4 h4 = hq4[q]; float w0, w1, w2, w3; \
    RDA(n0, w0) RDA(n1, w1) RDA(n2, w2) RDA(n3, w3) \
    s2 = fmaf(h4.x, w0, s2); s2 = fmaf(h4.y, w1, s2); \
    s2 = fmaf(h4.z, w2, s2); s2 = fmaf(h4.w, w3, s2); }
#define PF_XB(i) xb##i = xg4[(size_t)(t + 1) * xstride4 + (i)];
#define PF_XA(i) xa##i = xg4[(size_t)(t + 2) * xstride4 + (i)];

  for (int t = 0; t < T_DIM; t += 2) {
    // ---- even step: reads h0, consumes xa, writes h1; prefetch xb(t+1) ----
    REP8(PF_XB)
    {
      const int dep_ = 2 * t;                  // blocks CSE with odd half
      const float4* hq4 = reinterpret_cast<const float4*>(h0);
      float s1 = 0.f;
      X_LIST(S1A)
      float s2 = 0.f;
      Q_LIST(S2Q)
      float a  = __fadd_rn(__fadd_rn(s1, s2), bj);
      float th = xla_tanh_fma_f32(a);
      hown = __fadd_rn(hown, th);
      h1[j] = hown;
      __syncthreads();
      // store AFTER barrier: vmcnt drain hides under the next step.
      out[(size_t)t * (B_DIM * H_DIM) + out_row] = hown;
    }
    // ---- odd step: reads h1, consumes xb, writes h0; prefetch xa(t+2) ----
    if (t + 2 < T_DIM) { REP8(PF_XA) }
    {
      const int dep_ = 2 * t + 1;
      const float4* hq4 = reinterpret_cast<const float4*>(h1);
      float s1 = 0.f;
      X_LIST(S1B)
      float s2 = 0.f;
      Q_LIST(S2Q)
      float a  = __fadd_rn(__fadd_rn(s1, s2), bj);
      float th = xla_tanh_fma_f32(a);
      hown = __fadd_rn(hown, th);
      h0[j] = hown;
      __syncthreads();
      out[(size_t)(t + 1) * (B_DIM * H_DIM) + out_row] = hown;
    }
  }

  // final_state = h after last step (== outputs[T-1])
  out[(size_t)T_DIM * B_DIM * H_DIM + out_row] = hown;
}

extern "C" void kernel_launch(void* const* d_in, const int* in_sizes, int n_in,
                              void* d_out, int out_size, void* d_ws, size_t ws_size,
                              hipStream_t stream) {
  const float* x     = (const float*)d_in[0];
  const float* state = (const float*)d_in[1];
  const float* W_in  = (const float*)d_in[2];
  const float* W_h   = (const float*)d_in[3];
  const float* bias  = (const float*)d_in[4];
  float* out = (float*)d_out;

  diffeq_kernel<<<B_DIM, 128, 0, stream>>>(x, state, W_in, W_h, bias, out);
}

// Round 23
// 832.631 us; speedup vs baseline: 2.2636x; 1.5934x over previous
//
#include <hip/hip_runtime.h>
#include <math.h>

#define T_DIM 1024
#define B_DIM 256
#define D_DIM 32
#define H_DIM 128

// Bit-faithful XLA-CPU / Eigen fast-tanh, WITH-FMA variant — FROZEN.
// Verified bit-exact vs the harness reference (absmax 0.0, rounds 15-22).
__device__ __forceinline__ float xla_tanh_fma_f32(float x) {
  const float plim = 7.99881172180175781f;
  float xc = fminf(fmaxf(x, -plim), plim);
  float x2 = __fmul_rn(xc, xc);
  float p;
  p = fmaf(x2, -2.76076847742355e-16f, 2.00018790482477e-13f);
  p = fmaf(x2, p, -8.60467152213735e-11f);
  p = fmaf(x2, p,  5.12229709037114e-08f);
  p = fmaf(x2, p,  1.48572235717979e-05f);
  p = fmaf(x2, p,  6.37261928875436e-04f);
  p = fmaf(x2, p,  4.89352455891786e-03f);
  float num = __fmul_rn(xc, p);
  float q;
  q = fmaf(x2, 1.19825839466702e-06f, 1.18534705686654e-04f);
  q = fmaf(x2, q, 2.26843463243900e-03f);
  q = fmaf(x2, q, 4.89352518554385e-03f);
  float r = __fdiv_rn(num, q);
  return (fabsf(x) < 0.0004f) ? x : r;
}

// Accumulator hop: lane L receives lane L-1's value (row_shr:1, exact bit
// copy). Row-boundary / group-boundary lanes receive garbage — harmless,
// only the "active" lane of each 4-lane group carries the true partial.
__device__ __forceinline__ float dpp_shr1(float v) {
  return __int_as_float(__builtin_amdgcn_update_dpp(
      __float_as_int(v), __float_as_int(v), 0x111, 0xf, 0xf, false));
}

// 4-lane systolic split of the FROZEN serial chain (bit-exact):
// lane 4p+i owns W_h rows [32i,32i+32) and W_in rows [8i,8i+8) of column p.
// Round r: all lanes run the same 32(+8) serial fmaf body on their own
// operands; the true partial lives in lane i==r and hops i -> i+1 between
// rounds. After round 3, lane 4p+3 holds EXACTLY the ascending-k serial
// dot (k=0..127 / 0..31) — identical rounding to the verified R15 kernel.
// This shrinks the per-lane weight set 160 -> 40 regs, which is what the
// allocator refused to keep resident in rounds 17-22.
__global__ __launch_bounds__(512, 1) void diffeq_kernel(
    const float* __restrict__ x, const float* __restrict__ state,
    const float* __restrict__ W_in, const float* __restrict__ W_h,
    const float* __restrict__ bias, float* __restrict__ out) {
  __shared__ __align__(16) float h0[H_DIM];
  __shared__ __align__(16) float h1[H_DIM];

  const int b   = blockIdx.x;
  const int tid = threadIdx.x;          // 0..511
  const int p   = tid >> 2;             // output index 0..127
  const int i   = tid & 3;              // quarter 0..3 (same wave: 4|64)

  // ---- this lane's weight slices (constant-indexed arrays -> SROA) ----
  float wh[32];
#pragma unroll
  for (int m = 0; m < 32; ++m) wh[m] = W_h[(32 * i + m) * H_DIM + p];
  float wx[8];
#pragma unroll
  for (int m = 0; m < 8; ++m) wx[m] = W_in[(8 * i + m) * H_DIM + p];
  const float bj = bias[p];
  float hown = state[(size_t)b * H_DIM + p];  // true only on lane i==3

  if (tid < H_DIM) h0[tid] = state[(size_t)b * H_DIM + tid];

  const size_t out_row = (size_t)b * H_DIM + p;
  const float4* xg4 = reinterpret_cast<const float4*>(x + (size_t)b * D_DIM);
  const int xs4 = B_DIM * D_DIM / 4;    // float4 stride per t

  // per-lane x quads: lane needs x[8i..8i+7] = quads 2i, 2i+1 (same 128B
  // line per wave; double-buffered in regs, issued one step early).
  float4 xa0 = xg4[2 * i], xa1 = xg4[2 * i + 1];
  float4 xb0, xb1;
  __syncthreads();

#define S2Q4(Q, W) \
    s2 = fmaf(Q.x, wh[(W) + 0], s2); s2 = fmaf(Q.y, wh[(W) + 1], s2); \
    s2 = fmaf(Q.z, wh[(W) + 2], s2); s2 = fmaf(Q.w, wh[(W) + 3], s2);
#define S1Q4(Q, W) \
    s1 = fmaf(Q.x, wx[(W) + 0], s1); s1 = fmaf(Q.y, wx[(W) + 1], s1); \
    s1 = fmaf(Q.z, wx[(W) + 2], s1); s1 = fmaf(Q.w, wx[(W) + 3], s1);

#define STEP(HRD, HWR, X0, X1, TIDX) { \
    const float4* hb4 = reinterpret_cast<const float4*>(HRD); \
    float4 hqa = hb4[8 * i + 0], hqb = hb4[8 * i + 1]; \
    float4 hqc = hb4[8 * i + 2], hqd = hb4[8 * i + 3]; \
    float4 hqe = hb4[8 * i + 4], hqf = hb4[8 * i + 5]; \
    float4 hqg = hb4[8 * i + 6], hqh = hb4[8 * i + 7]; \
    float s1 = 0.f, s2 = 0.f; \
    _Pragma("unroll") \
    for (int r = 0; r < 4; ++r) { \
      S2Q4(hqa, 0)  S2Q4(hqb, 4)  S2Q4(hqc, 8)  S2Q4(hqd, 12) \
      S2Q4(hqe, 16) S2Q4(hqf, 20) S2Q4(hqg, 24) S2Q4(hqh, 28) \
      S1Q4(X0, 0)   S1Q4(X1, 4) \
      if (r < 3) { s1 = dpp_shr1(s1); s2 = dpp_shr1(s2); } \
    } \
    float a  = __fadd_rn(__fadd_rn(s1, s2), bj); \
    float th = xla_tanh_fma_f32(a); \
    float hv = __fadd_rn(hown, th); \
    if (i == 3) (HWR)[p] = hv; \
    hown = hv;  /* only lane 3's is meaningful */ \
    __syncthreads(); \
    if (i == 3) out[(size_t)(TIDX) * (B_DIM * H_DIM) + out_row] = hv; \
  }

  for (int t = 0; t < T_DIM; t += 2) {
    // even step: h0 -> h1, consumes xa; prefetch xb for t+1
    xb0 = xg4[(size_t)(t + 1) * xs4 + 2 * i];
    xb1 = xg4[(size_t)(t + 1) * xs4 + 2 * i + 1];
    STEP(h0, h1, xa0, xa1, t)
    // odd step: h1 -> h0, consumes xb; prefetch xa for t+2 (clamped)
    {
      int t2 = (t + 2 < T_DIM) ? (t + 2) : (T_DIM - 1);
      xa0 = xg4[(size_t)t2 * xs4 + 2 * i];
      xa1 = xg4[(size_t)t2 * xs4 + 2 * i + 1];
    }
    STEP(h1, h0, xb0, xb1, t + 1)
  }

  // final_state = h after last step (== outputs[T-1])
  if (i == 3) out[(size_t)T_DIM * B_DIM * H_DIM + out_row] = hown;
}

extern "C" void kernel_launch(void* const* d_in, const int* in_sizes, int n_in,
                              void* d_out, int out_size, void* d_ws, size_t ws_size,
                              hipStream_t stream) {
  const float* x     = (const float*)d_in[0];
  const float* state = (const float*)d_in[1];
  const float* W_in  = (const float*)d_in[2];
  const float* W_h   = (const float*)d_in[3];
  const float* bias  = (const float*)d_in[4];
  float* out = (float*)d_out;

  diffeq_kernel<<<B_DIM, 512, 0, stream>>>(x, state, W_in, W_h, bias, out);
}

// Round 24
// 757.427 us; speedup vs baseline: 2.4884x; 1.0993x over previous
//
#include <hip/hip_runtime.h>
#include <math.h>

#define T_DIM 1024
#define B_DIM 256
#define D_DIM 32
#define H_DIM 128
#define HPAD 36   // 32 data + 4 pad floats per 32-float group (9 quads)

// Bit-faithful XLA-CPU / Eigen fast-tanh, WITH-FMA variant — FROZEN.
// Verified bit-exact vs the harness reference (absmax 0.0, rounds 15-23).
__device__ __forceinline__ float xla_tanh_fma_f32(float x) {
  const float plim = 7.99881172180175781f;
  float xc = fminf(fmaxf(x, -plim), plim);
  float x2 = __fmul_rn(xc, xc);
  float p;
  p = fmaf(x2, -2.76076847742355e-16f, 2.00018790482477e-13f);
  p = fmaf(x2, p, -8.60467152213735e-11f);
  p = fmaf(x2, p,  5.12229709037114e-08f);
  p = fmaf(x2, p,  1.48572235717979e-05f);
  p = fmaf(x2, p,  6.37261928875436e-04f);
  p = fmaf(x2, p,  4.89352455891786e-03f);
  float num = __fmul_rn(xc, p);
  float q;
  q = fmaf(x2, 1.19825839466702e-06f, 1.18534705686654e-04f);
  q = fmaf(x2, q, 2.26843463243900e-03f);
  q = fmaf(x2, q, 4.89352518554385e-03f);
  float r = __fdiv_rn(num, q);
  return (fabsf(x) < 0.0004f) ? x : r;
}

// Accumulator hop: lane L receives lane L-1's value (row_shr:1, exact bit
// copy). Only the active lane of each 4-lane group carries the true partial.
__device__ __forceinline__ float dpp_shr1(float v) {
  return __int_as_float(__builtin_amdgcn_update_dpp(
      __float_as_int(v), __float_as_int(v), 0x111, 0xf, 0xf, false));
}

// 4-lane systolic split of the FROZEN serial chain (bit-exact), R23 + the
// bank-conflict fix: h buffers padded to stride HPAD=36 floats per 32-float
// group, so read #m hits banks (4i+4m+c)%32 — the four i-groups land 4
// banks apart (R23's unpadded layout had all groups on the same banks:
// 6.7e7 conflict-cycles/dispatch, on the post-barrier critical path).
__global__ __launch_bounds__(512, 1) void diffeq_kernel(
    const float* __restrict__ x, const float* __restrict__ state,
    const float* __restrict__ W_in, const float* __restrict__ W_h,
    const float* __restrict__ bias, float* __restrict__ out) {
  __shared__ __align__(16) float h0[4 * HPAD];
  __shared__ __align__(16) float h1[4 * HPAD];

  const int b   = blockIdx.x;
  const int tid = threadIdx.x;          // 0..511
  const int p   = tid >> 2;             // output index 0..127
  const int i   = tid & 3;              // quarter 0..3 (4 | 64: same wave)

  // ---- this lane's weight slices (constant-indexed -> SROA) ----
  float wh[32];
#pragma unroll
  for (int m = 0; m < 32; ++m) wh[m] = W_h[(32 * i + m) * H_DIM + p];
  float wx[8];
#pragma unroll
  for (int m = 0; m < 8; ++m) wx[m] = W_in[(8 * i + m) * H_DIM + p];
  const float bj = bias[p];
  float hown = state[(size_t)b * H_DIM + p];  // true only on lane i==3

  if (tid < H_DIM)
    h0[HPAD * (tid >> 5) + (tid & 31)] = state[(size_t)b * H_DIM + tid];

  const size_t out_row = (size_t)b * H_DIM + p;
  const float4* xg4 = reinterpret_cast<const float4*>(x + (size_t)b * D_DIM);
  const int xs4 = B_DIM * D_DIM / 4;    // float4 stride per t

  // per-lane x quads (lane needs x[8i..8i+7]); double-buffered in regs.
  float4 xa0 = xg4[2 * i], xa1 = xg4[2 * i + 1];
  float4 xb0, xb1;
  __syncthreads();

#define S2Q4(Q, W) \
    s2 = fmaf(Q.x, wh[(W) + 0], s2); s2 = fmaf(Q.y, wh[(W) + 1], s2); \
    s2 = fmaf(Q.z, wh[(W) + 2], s2); s2 = fmaf(Q.w, wh[(W) + 3], s2);
#define S1Q4(Q, W) \
    s1 = fmaf(Q.x, wx[(W) + 0], s1); s1 = fmaf(Q.y, wx[(W) + 1], s1); \
    s1 = fmaf(Q.z, wx[(W) + 2], s1); s1 = fmaf(Q.w, wx[(W) + 3], s1);

#define STEP(HRD, HWR, X0, X1, TIDX) { \
    const float4* hb4 = reinterpret_cast<const float4*>(HRD); \
    float4 hqa = hb4[9 * i + 0], hqb = hb4[9 * i + 1]; \
    float4 hqc = hb4[9 * i + 2], hqd = hb4[9 * i + 3]; \
    float4 hqe = hb4[9 * i + 4], hqf = hb4[9 * i + 5]; \
    float4 hqg = hb4[9 * i + 6], hqh = hb4[9 * i + 7]; \
    float s1 = 0.f, s2 = 0.f; \
    _Pragma("unroll") \
    for (int r = 0; r < 4; ++r) { \
      S1Q4(X0, 0)   S1Q4(X1, 4) \
      S2Q4(hqa, 0)  S2Q4(hqb, 4)  S2Q4(hqc, 8)  S2Q4(hqd, 12) \
      S2Q4(hqe, 16) S2Q4(hqf, 20) S2Q4(hqg, 24) S2Q4(hqh, 28) \
      if (r < 3) { s1 = dpp_shr1(s1); s2 = dpp_shr1(s2); } \
    } \
    float a  = __fadd_rn(__fadd_rn(s1, s2), bj); \
    float th = xla_tanh_fma_f32(a); \
    float hv = __fadd_rn(hown, th); \
    if (i == 3) (HWR)[HPAD * (p >> 5) + (p & 31)] = hv; \
    hown = hv;  /* only lane 3's is meaningful */ \
    __syncthreads(); \
    if (i == 3) out[(size_t)(TIDX) * (B_DIM * H_DIM) + out_row] = hv; \
  }

  for (int t = 0; t < T_DIM; t += 2) {
    // even step: h0 -> h1, consumes xa; prefetch xb for t+1
    xb0 = xg4[(size_t)(t + 1) * xs4 + 2 * i];
    xb1 = xg4[(size_t)(t + 1) * xs4 + 2 * i + 1];
    STEP(h0, h1, xa0, xa1, t)
    // odd step: h1 -> h0, consumes xb; prefetch xa for t+2 (clamped)
    {
      int t2 = (t + 2 < T_DIM) ? (t + 2) : (T_DIM - 1);
      xa0 = xg4[(size_t)t2 * xs4 + 2 * i];
      xa1 = xg4[(size_t)t2 * xs4 + 2 * i + 1];
    }
    STEP(h1, h0, xb0, xb1, t + 1)
  }

  // final_state = h after last step (== outputs[T-1])
  if (i == 3) out[(size_t)T_DIM * B_DIM * H_DIM + out_row] = hown;
}

extern "C" void kernel_launch(void* const* d_in, const int* in_sizes, int n_in,
                              void* d_out, int out_size, void* d_ws, size_t ws_size,
                              hipStream_t stream) {
  const float* x     = (const float*)d_in[0];
  const float* state = (const float*)d_in[1];
  const float* W_in  = (const float*)d_in[2];
  const float* W_h   = (const float*)d_in[3];
  const float* bias  = (const float*)d_in[4];
  float* out = (float*)d_out;

  diffeq_kernel<<<B_DIM, 512, 0, stream>>>(x, state, W_in, W_h, bias, out);
}

// Round 25
// 683.068 us; speedup vs baseline: 2.7593x; 1.1089x over previous
//
#include <hip/hip_runtime.h>
#include <math.h>

#define T_DIM 1024
#define B_DIM 256
#define D_DIM 32
#define H_DIM 128

// Bit-faithful XLA-CPU / Eigen fast-tanh, WITH-FMA variant — FROZEN.
// Verified bit-exact vs the harness reference (absmax 0.0, rounds 15-24).
__device__ __forceinline__ float xla_tanh_fma_f32(float x) {
  const float plim = 7.99881172180175781f;
  float xc = fminf(fmaxf(x, -plim), plim);
  float x2 = __fmul_rn(xc, xc);
  float p;
  p = fmaf(x2, -2.76076847742355e-16f, 2.00018790482477e-13f);
  p = fmaf(x2, p, -8.60467152213735e-11f);
  p = fmaf(x2, p,  5.12229709037114e-08f);
  p = fmaf(x2, p,  1.48572235717979e-05f);
  p = fmaf(x2, p,  6.37261928875436e-04f);
  p = fmaf(x2, p,  4.89352455891786e-03f);
  float num = __fmul_rn(xc, p);
  float q;
  q = fmaf(x2, 1.19825839466702e-06f, 1.18534705686654e-04f);
  q = fmaf(x2, q, 2.26843463243900e-03f);
  q = fmaf(x2, q, 4.89352518554385e-03f);
  float r = __fdiv_rn(num, q);
  return (fabsf(x) < 0.0004f) ? x : r;
}

// Accumulator hop: lane L receives lane L-1 (row_shr:1, exact bit copy).
__device__ __forceinline__ float dpp_shr1(float v) {
  return __int_as_float(__builtin_amdgcn_update_dpp(
      __float_as_int(v), __float_as_int(v), 0x111, 0xf, 0xf, false));
}

// 2-LANE systolic split of the FROZEN serial chain (bit-exact).
// R24 was issue-bound (VALUBusy 90%): the systolic scheme issues the full
// K FMAs per LANE regardless of split width, so total issue scales with
// lane count. 2-way × 256 threads (1 wave/SIMD, all 4 SIMDs busy) halves
// per-SIMD issue vs R24's 4-way × 512 while the serial chain (the bit-exact
// floor: 128 dependent FMA + tanh) is unchanged.
// Lane 2p+i owns W_h rows [64i,64i+64) and W_in rows [16i,16i+16) of col p
// (80 weight VGPRs). Round 0 on lane 0 from acc=0, dpp hop, round 1 on
// lane 1 — exactly R15's ascending-k serial fmaf chain.
// h-quad LDS reads touch only 2 distinct addresses per instruction
// (broadcast x2 = conflict-free); h re-read per round to cap live VGPRs.
__global__ __launch_bounds__(256, 1) void diffeq_kernel(
    const float* __restrict__ x, const float* __restrict__ state,
    const float* __restrict__ W_in, const float* __restrict__ W_h,
    const float* __restrict__ bias, float* __restrict__ out) {
  __shared__ __align__(16) float h0[H_DIM];
  __shared__ __align__(16) float h1[H_DIM];

  const int b   = blockIdx.x;
  const int tid = threadIdx.x;          // 0..255
  const int p   = tid >> 1;             // output index 0..127
  const int i   = tid & 1;              // half 0..1 (pairs lane-aligned)

  // ---- this lane's weight slices (constant-indexed -> SROA) ----
  float wh[64];
#pragma unroll
  for (int m = 0; m < 64; ++m) wh[m] = W_h[(64 * i + m) * H_DIM + p];
  float wx[16];
#pragma unroll
  for (int m = 0; m < 16; ++m) wx[m] = W_in[(16 * i + m) * H_DIM + p];
  const float bj = bias[p];
  float hown = state[(size_t)b * H_DIM + p];  // true only on lane i==1

  if (tid < H_DIM) h0[tid] = state[(size_t)b * H_DIM + tid];

  const size_t out_row = (size_t)b * H_DIM + p;
  const float4* xg4 = reinterpret_cast<const float4*>(x + (size_t)b * D_DIM);
  const int xs4 = B_DIM * D_DIM / 4;    // float4 stride per t
  __syncthreads();

#define STEP(HRD, HWR, TIDX) { \
    const float4* hb4 = reinterpret_cast<const float4*>(HRD); \
    const float4* xr4 = xg4 + (size_t)(TIDX) * xs4 + 4 * i; \
    float4 xq0 = xr4[0], xq1 = xr4[1], xq2 = xr4[2], xq3 = xr4[3]; \
    float s1 = 0.f, s2 = 0.f; \
    _Pragma("unroll") \
    for (int r = 0; r < 2; ++r) { \
      _Pragma("unroll") \
      for (int m = 0; m < 16; ++m) { \
        float4 h4 = hb4[16 * i + m]; \
        s2 = fmaf(h4.x, wh[4 * m + 0], s2); \
        s2 = fmaf(h4.y, wh[4 * m + 1], s2); \
        s2 = fmaf(h4.z, wh[4 * m + 2], s2); \
        s2 = fmaf(h4.w, wh[4 * m + 3], s2); \
      } \
      s1 = fmaf(xq0.x, wx[0],  s1); s1 = fmaf(xq0.y, wx[1],  s1); \
      s1 = fmaf(xq0.z, wx[2],  s1); s1 = fmaf(xq0.w, wx[3],  s1); \
      s1 = fmaf(xq1.x, wx[4],  s1); s1 = fmaf(xq1.y, wx[5],  s1); \
      s1 = fmaf(xq1.z, wx[6],  s1); s1 = fmaf(xq1.w, wx[7],  s1); \
      s1 = fmaf(xq2.x, wx[8],  s1); s1 = fmaf(xq2.y, wx[9],  s1); \
      s1 = fmaf(xq2.z, wx[10], s1); s1 = fmaf(xq2.w, wx[11], s1); \
      s1 = fmaf(xq3.x, wx[12], s1); s1 = fmaf(xq3.y, wx[13], s1); \
      s1 = fmaf(xq3.z, wx[14], s1); s1 = fmaf(xq3.w, wx[15], s1); \
      if (r < 1) { s1 = dpp_shr1(s1); s2 = dpp_shr1(s2); } \
    } \
    float a  = __fadd_rn(__fadd_rn(s1, s2), bj); \
    float th = xla_tanh_fma_f32(a); \
    float hv = __fadd_rn(hown, th); \
    if (i == 1) (HWR)[p] = hv; \
    hown = hv;  /* only lane 1's is meaningful */ \
    __syncthreads(); \
    if (i == 1) out[(size_t)(TIDX) * (B_DIM * H_DIM) + out_row] = hv; \
  }

  for (int t = 0; t < T_DIM; t += 2) {
    STEP(h0, h1, t)        // even: h0 -> h1
    STEP(h1, h0, t + 1)    // odd:  h1 -> h0
  }

  // final_state = h after last step (== outputs[T-1])
  if (i == 1) out[(size_t)T_DIM * B_DIM * H_DIM + out_row] = hown;
}

extern "C" void kernel_launch(void* const* d_in, const int* in_sizes, int n_in,
                              void* d_out, int out_size, void* d_ws, size_t ws_size,
                              hipStream_t stream) {
  const float* x     = (const float*)d_in[0];
  const float* state = (const float*)d_in[1];
  const float* W_in  = (const float*)d_in[2];
  const float* W_h   = (const float*)d_in[3];
  const float* bias  = (const float*)d_in[4];
  float* out = (float*)d_out;

  diffeq_kernel<<<B_DIM, 256, 0, stream>>>(x, state, W_in, W_h, bias, out);
}

// Round 26
// 652.335 us; speedup vs baseline: 2.8893x; 1.0471x over previous
//
#include <hip/hip_runtime.h>
#include <math.h>

#define T_DIM 1024
#define B_DIM 256
#define D_DIM 32
#define H_DIM 128
#define HP 68   // float stride between the two 64-float h halves (17 quads)

// Bit-faithful XLA-CPU / Eigen fast-tanh, WITH-FMA variant — FROZEN.
// Verified bit-exact vs the harness reference (absmax 0.0, rounds 15-25).
__device__ __forceinline__ float xla_tanh_fma_f32(float x) {
  const float plim = 7.99881172180175781f;
  float xc = fminf(fmaxf(x, -plim), plim);
  float x2 = __fmul_rn(xc, xc);
  float p;
  p = fmaf(x2, -2.76076847742355e-16f, 2.00018790482477e-13f);
  p = fmaf(x2, p, -8.60467152213735e-11f);
  p = fmaf(x2, p,  5.12229709037114e-08f);
  p = fmaf(x2, p,  1.48572235717979e-05f);
  p = fmaf(x2, p,  6.37261928875436e-04f);
  p = fmaf(x2, p,  4.89352455891786e-03f);
  float num = __fmul_rn(xc, p);
  float q;
  q = fmaf(x2, 1.19825839466702e-06f, 1.18534705686654e-04f);
  q = fmaf(x2, q, 2.26843463243900e-03f);
  q = fmaf(x2, q, 4.89352518554385e-03f);
  float r = __fdiv_rn(num, q);
  return (fabsf(x) < 0.0004f) ? x : r;
}

// Accumulator hop: lane L receives lane L-1 (row_shr:1, exact bit copy).
__device__ __forceinline__ float dpp_shr1(float v) {
  return __int_as_float(__builtin_amdgcn_update_dpp(
      __float_as_int(v), __float_as_int(v), 0x111, 0xf, 0xf, false));
}

// 2-lane systolic split of the FROZEN serial chain (bit-exact), R25 plus:
//  - h halves PADDED to stride HP=68 floats: i=0 reads banks 4m..4m+3,
//    i=1 reads banks 4m+4..4m+7 (disjoint) — R25's unpadded layout had
//    both broadcast groups on the SAME banks (words 64+4m = 4m mod 32),
//    2-way serializing every post-barrier h read (6.7e7 conflict cycles).
//  - x quads double-buffered in registers again (R25 loaded them in-step).
__global__ __launch_bounds__(256, 1) void diffeq_kernel(
    const float* __restrict__ x, const float* __restrict__ state,
    const float* __restrict__ W_in, const float* __restrict__ W_h,
    const float* __restrict__ bias, float* __restrict__ out) {
  __shared__ __align__(16) float h0[2 * HP];
  __shared__ __align__(16) float h1[2 * HP];

  const int b   = blockIdx.x;
  const int tid = threadIdx.x;          // 0..255
  const int p   = tid >> 1;             // output index 0..127
  const int i   = tid & 1;              // half 0..1 (pairs lane-aligned)

  // ---- this lane's weight slices (constant-indexed -> SROA) ----
  float wh[64];
#pragma unroll
  for (int m = 0; m < 64; ++m) wh[m] = W_h[(64 * i + m) * H_DIM + p];
  float wx[16];
#pragma unroll
  for (int m = 0; m < 16; ++m) wx[m] = W_in[(16 * i + m) * H_DIM + p];
  const float bj = bias[p];
  float hown = state[(size_t)b * H_DIM + p];  // true only on lane i==1

  if (tid < H_DIM)
    h0[HP * (tid >> 6) + (tid & 63)] = state[(size_t)b * H_DIM + tid];

  const size_t out_row = (size_t)b * H_DIM + p;
  const float4* xg4 = reinterpret_cast<const float4*>(x + (size_t)b * D_DIM);
  const int xs4 = B_DIM * D_DIM / 4;    // float4 stride per t

  // x quads double-buffered in named registers (lane needs quads 4i..4i+3).
  float4 xa0, xa1, xa2, xa3, xb0, xb1, xb2, xb3;
  {
    const float4* xp = xg4 + 4 * i;     // t = 0
    xa0 = xp[0]; xa1 = xp[1]; xa2 = xp[2]; xa3 = xp[3];
  }
  __syncthreads();

#define STEP(HRD, HWR, X0, X1, X2, X3, TIDX) { \
    const float4* hb4 = reinterpret_cast<const float4*>(HRD); \
    float s1 = 0.f, s2 = 0.f; \
    _Pragma("unroll") \
    for (int r = 0; r < 2; ++r) { \
      _Pragma("unroll") \
      for (int m = 0; m < 16; ++m) { \
        float4 h4 = hb4[17 * i + m];     /* padded: bank-disjoint halves */ \
        s2 = fmaf(h4.x, wh[4 * m + 0], s2); \
        s2 = fmaf(h4.y, wh[4 * m + 1], s2); \
        s2 = fmaf(h4.z, wh[4 * m + 2], s2); \
        s2 = fmaf(h4.w, wh[4 * m + 3], s2); \
      } \
      s1 = fmaf(X0.x, wx[0],  s1); s1 = fmaf(X0.y, wx[1],  s1); \
      s1 = fmaf(X0.z, wx[2],  s1); s1 = fmaf(X0.w, wx[3],  s1); \
      s1 = fmaf(X1.x, wx[4],  s1); s1 = fmaf(X1.y, wx[5],  s1); \
      s1 = fmaf(X1.z, wx[6],  s1); s1 = fmaf(X1.w, wx[7],  s1); \
      s1 = fmaf(X2.x, wx[8],  s1); s1 = fmaf(X2.y, wx[9],  s1); \
      s1 = fmaf(X2.z, wx[10], s1); s1 = fmaf(X2.w, wx[11], s1); \
      s1 = fmaf(X3.x, wx[12], s1); s1 = fmaf(X3.y, wx[13], s1); \
      s1 = fmaf(X3.z, wx[14], s1); s1 = fmaf(X3.w, wx[15], s1); \
      if (r < 1) { s1 = dpp_shr1(s1); s2 = dpp_shr1(s2); } \
    } \
    float a  = __fadd_rn(__fadd_rn(s1, s2), bj); \
    float th = xla_tanh_fma_f32(a); \
    float hv = __fadd_rn(hown, th); \
    if (i == 1) (HWR)[HP * (p >> 6) + (p & 63)] = hv; \
    hown = hv;  /* only lane 1's is meaningful */ \
    __syncthreads(); \
    if (i == 1) out[(size_t)(TIDX) * (B_DIM * H_DIM) + out_row] = hv; \
  }

  for (int t = 0; t < T_DIM; t += 2) {
    // even step: h0 -> h1, consumes xa; prefetch xb for t+1
    {
      const float4* xp = xg4 + (size_t)(t + 1) * xs4 + 4 * i;
      xb0 = xp[0]; xb1 = xp[1]; xb2 = xp[2]; xb3 = xp[3];
    }
    STEP(h0, h1, xa0, xa1, xa2, xa3, t)
    // odd step: h1 -> h0, consumes xb; prefetch xa for t+2 (clamped)
    {
      int t2 = (t + 2 < T_DIM) ? (t + 2) : (T_DIM - 1);
      const float4* xp = xg4 + (size_t)t2 * xs4 + 4 * i;
      xa0 = xp[0]; xa1 = xp[1]; xa2 = xp[2]; xa3 = xp[3];
    }
    STEP(h1, h0, xb0, xb1, xb2, xb3, t + 1)
  }

  // final_state = h after last step (== outputs[T-1])
  if (i == 1) out[(size_t)T_DIM * B_DIM * H_DIM + out_row] = hown;
}

extern "C" void kernel_launch(void* const* d_in, const int* in_sizes, int n_in,
                              void* d_out, int out_size, void* d_ws, size_t ws_size,
                              hipStream_t stream) {
  const float* x     = (const float*)d_in[0];
  const float* state = (const float*)d_in[1];
  const float* W_in  = (const float*)d_in[2];
  const float* W_h   = (const float*)d_in[3];
  const float* bias  = (const float*)d_in[4];
  float* out = (float*)d_out;

  diffeq_kernel<<<B_DIM, 256, 0, stream>>>(x, state, W_in, W_h, bias, out);
}